// Round 6
// baseline (168.783 us; speedup 1.0000x reference)
//
#include <hip/hip_runtime.h>
#include <hip/hip_bf16.h>
#include <math.h>

// R6: phased, ping-pong-staged pipeline (latency-chain removal).
//   featbuf (LDS, 2x per wave): packed bf16 features per point, written one
//     batch ahead -> phase A layer-1 B-frags are stall-free ds_read_b128.
//   phase A: 4x [read bfrag, 4 MFMA layer1, leaky+pack, transpose-write]
//   gap:     next batch's pos/dir loads + interp + featbuf write (hides RAW)
//   phase B: 4x [2x ds_read_b128 h-frag, 8 MFMA layer2 (C=ci direct), epilogue]
//   Barrier-free: all LDS wave-private; weights resident as A-fragments.

#define NTHREADS 256
#define NB 4                  // 64-point batches per wave
#define LSTRIDE 72            // shorts per transpose row (144 B, 16B-aligned)
#define WAVE_L (64 * LSTRIDE) // 9216 B per wave

typedef __attribute__((ext_vector_type(8))) short bf16x8;
typedef __attribute__((ext_vector_type(4))) float f32x4;
typedef __attribute__((ext_vector_type(4))) int i32x4;
typedef __attribute__((ext_vector_type(2))) int i32x2;

static __device__ __forceinline__ short f2bf(float f) {
    return __builtin_bit_cast(short, __float2bfloat16(f));  // RNE
}
static __device__ __forceinline__ int pk2(float lo, float hi) {
    unsigned short l = (unsigned short)f2bf(lo);
    unsigned short h = (unsigned short)f2bf(hi);
    return (int)(((unsigned int)h << 16) | (unsigned int)l);
}

static __device__ __forceinline__ void bilerp3(const float* __restrict__ g,
                                               float px, float py, float* f) {
    float fx = px * 255.0f;
    float fy = py * 255.0f;
    int x0 = (int)fx;            // trunc, fx >= 0
    int y0 = (int)fy;
    float xf = fx - floorf(fx);  // jnp.mod(fx, 1.0), fx >= 0
    float yf = fy - floorf(fy);
    int x1 = min(x0 + 1, 255);
    int y1 = min(y0 + 1, 255);
    const float* r00 = g + (y0 * 256 + x0) * 3;
    const float* r01 = g + (y0 * 256 + x1) * 3;
    const float* r10 = g + (y1 * 256 + x0) * 3;
    const float* r11 = g + (y1 * 256 + x1) * 3;
#pragma unroll
    for (int ch = 0; ch < 3; ++ch) {
        float tl = r00[ch], tr = r01[ch], bl = r10[ch], br = r11[ch];
        float top = fmaf(xf, tr - tl, tl);
        float bot = fmaf(xf, br - bl, bl);
        f[ch] = fmaf(yf, bot - top, top);
    }
}

__global__ __launch_bounds__(NTHREADS, 3) void mlp_mfma_kernel(
    const float* __restrict__ pos, const float* __restrict__ dir,
    const float* __restrict__ pos_grid, const float* __restrict__ dir_grid,
    const float* __restrict__ W1, const float* __restrict__ b1,
    const float* __restrict__ W2, const float* __restrict__ b2,
    const float* __restrict__ W3, const float* __restrict__ b3,
    float* __restrict__ out) {
    __shared__ short lds_L[4 * WAVE_L];     // transpose buffers, 36864 B
    __shared__ int lds_F[4 * 2 * 64 * 4];   // feature ping-pong, 8192 B

    const int w = threadIdx.x >> 6;
    const int lane = threadIdx.x & 63;
    const int c = lane & 15;
    const int q = lane >> 4;

    short* L = lds_L + w * WAVE_L;
    int* FB = lds_F + w * (2 * 64 * 4);

    // ---- resident weight fragments (weights are the MFMA A operand) ----
    // layer1 A-frag: A[m=f][k]; f = mt*16+c, k = q*8+j. q==0: W1 row + b1@k=6.
    bf16x8 A1f[4];
#pragma unroll
    for (int mt = 0; mt < 4; ++mt) {
        int f = mt * 16 + c;
        bf16x8 t;
#pragma unroll
        for (int j = 0; j < 8; ++j) {
            float v = 0.0f;
            if (q == 0) {
                if (j < 6) v = W1[f * 6 + j];
                else if (j == 6) v = b1[f];
            }
            t[j] = f2bf(v);
        }
        A1f[mt] = t;
    }
    // layer2 A-frag: A[m=n2][k=f]; n2 = mt*16+c, k = kt*32+q*8+j.
    bf16x8 A2f[2][4];
#pragma unroll
    for (int kt = 0; kt < 2; ++kt)
#pragma unroll
        for (int mt = 0; mt < 4; ++mt) {
            int n2 = mt * 16 + c;
            int k0 = kt * 32 + q * 8;
            bf16x8 t;
#pragma unroll
            for (int j = 0; j < 8; ++j) t[j] = f2bf(W2[n2 * 64 + k0 + j]);
            A2f[kt][mt] = t;
        }
    // epilogue constants: n2 = ft*16 + q*4 + r
    f32x4 ci[4], w3q[4];
#pragma unroll
    for (int ft = 0; ft < 4; ++ft)
#pragma unroll
        for (int r = 0; r < 4; ++r) {
            ci[ft][r] = b2[ft * 16 + q * 4 + r];
            w3q[ft][r] = W3[ft * 16 + q * 4 + r];
        }
    const float b3s = b3[0];
    const int dbias = pk2(1.0f, 0.0f);  // features k=6 (bias), k=7 (zero)

    const long wave_global = (long)blockIdx.x * 4 + w;
    const long base0 = wave_global * (64L * NB);
    const f32x4 zacc = {0.f, 0.f, 0.f, 0.f};

    // ---- prologue: stage batch 0's features into featbuf[0] ----
    {
        float2 pp = ((const float2*)pos)[base0 + lane];
        float2 dd = ((const float2*)dir)[base0 + lane];
        float feat[6];
        bilerp3(pos_grid, pp.x, pp.y, feat);
        bilerp3(dir_grid, dd.x, dd.y, feat + 3);
        i32x4 dv;
        dv[0] = pk2(feat[0], feat[1]);
        dv[1] = pk2(feat[2], feat[3]);
        dv[2] = pk2(feat[4], feat[5]);
        dv[3] = dbias;
        *(i32x4*)(FB + lane * 4) = dv;  // buf 0, row = point
    }

#pragma unroll 1
    for (int ib = 0; ib < NB; ++ib) {
        const long base = base0 + ib * 64;
        const int cur = ib & 1;

        // ---- phase A: layer 1 for all 4 pt tiles + transpose writes ----
#pragma unroll
        for (int pt = 0; pt < 4; ++pt) {
            const int row = pt * 16 + c;
            i32x4 bi = *(const i32x4*)(FB + cur * 256 + row * 4);
            bf16x8 bfrag = __builtin_bit_cast(bf16x8, bi);
            f32x4 a1[4];
#pragma unroll
            for (int mt = 0; mt < 4; ++mt)
                a1[mt] = __builtin_amdgcn_mfma_f32_16x16x32_bf16(
                    A1f[mt], bfrag, zacc, 0, 0, 0);
#pragma unroll
            for (int mt = 0; mt < 4; ++mt) {
                float l0 = a1[mt][0], l1 = a1[mt][1];
                float l2 = a1[mt][2], l3 = a1[mt][3];
                l0 = fmaxf(l0, 0.01f * l0);
                l1 = fmaxf(l1, 0.01f * l1);
                l2 = fmaxf(l2, 0.01f * l2);
                l3 = fmaxf(l3, 0.01f * l3);
                i32x2 wv;
                wv[0] = pk2(l0, l1);
                wv[1] = pk2(l2, l3);
                *(i32x2*)(L + row * LSTRIDE + mt * 16 + q * 4) = wv;
            }
        }

        // ---- gap filler: interp NEXT batch, write other featbuf ----
        {
            const long nbase = (ib + 1 < NB) ? (base + 64) : base;
            float2 pp = ((const float2*)pos)[nbase + lane];
            float2 dd = ((const float2*)dir)[nbase + lane];
            float feat[6];
            bilerp3(pos_grid, pp.x, pp.y, feat);
            bilerp3(dir_grid, dd.x, dd.y, feat + 3);
            i32x4 dv;
            dv[0] = pk2(feat[0], feat[1]);
            dv[1] = pk2(feat[2], feat[3]);
            dv[2] = pk2(feat[4], feat[5]);
            dv[3] = dbias;
            *(i32x4*)(FB + (cur ^ 1) * 256 + lane * 4) = dv;
        }

        // ---- phase B: layer 2 + epilogue (compiler inserts lgkmcnt RAW wait) ----
        float s[4];
#pragma unroll
        for (int pt = 0; pt < 4; ++pt) {
            const int row = pt * 16 + c;
            bf16x8 h0 = *(const bf16x8*)(L + row * LSTRIDE + q * 8);
            bf16x8 h1 = *(const bf16x8*)(L + row * LSTRIDE + 32 + q * 8);
            float t = 0.0f;
#pragma unroll
            for (int ft = 0; ft < 4; ++ft) {
                f32x4 t0 = __builtin_amdgcn_mfma_f32_16x16x32_bf16(
                    A2f[0][ft], h0, ci[ft], 0, 0, 0);  // C = b2 directly
                f32x4 a2 = __builtin_amdgcn_mfma_f32_16x16x32_bf16(
                    A2f[1][ft], h1, t0, 0, 0, 0);
#pragma unroll
                for (int r = 0; r < 4; ++r) {
                    float x = a2[r];
                    x = fmaxf(x, 0.01f * x);
                    t = fmaf(x, w3q[ft][r], t);
                }
            }
            t += __shfl_xor(t, 16, 64);
            t += __shfl_xor(t, 32, 64);
            s[pt] = t;
        }

        // lane (c,q) emits point p = q*16 + c with value s[q]
        float sa = (q & 1) ? s[1] : s[0];
        float sb = (q & 1) ? s[3] : s[2];
        float v = (q & 2) ? sb : sa;
        v += b3s;
        v = 1.0f / (1.0f + __expf(-v));
        out[base + q * 16 + c] = v;
    }
}

extern "C" void kernel_launch(void* const* d_in, const int* in_sizes, int n_in,
                              void* d_out, int out_size, void* d_ws,
                              size_t ws_size, hipStream_t stream) {
    const float* pos = (const float*)d_in[0];
    const float* dir = (const float*)d_in[1];
    const float* pos_grid = (const float*)d_in[2];
    const float* dir_grid = (const float*)d_in[3];
    const float* W1 = (const float*)d_in[4];
    const float* b1 = (const float*)d_in[5];
    const float* W2 = (const float*)d_in[6];
    const float* b2 = (const float*)d_in[7];
    const float* W3 = (const float*)d_in[8];
    const float* b3 = (const float*)d_in[9];
    float* out = (float*)d_out;

    const int n = in_sizes[0] / 2;   // points
    const int batches = n / 64;      // 32768 for N=2M
    const int waves = batches / NB;  // 8192
    const int blocks = waves / 4;    // 2048

    mlp_mfma_kernel<<<blocks, NTHREADS, 0, stream>>>(
        pos, dir, pos_grid, dir_grid, W1, b1, W2, b2, W3, b3, out);
}

// Round 7
// 160.688 us; speedup vs baseline: 1.0504x; 1.0504x over previous
//
#include <hip/hip_runtime.h>
#include <hip/hip_bf16.h>
#include <math.h>

// R7: gather-bound fix.
//   Preproc kernel: per (y0,x0) pack the 2x2x3 corner patch as 12 bf16 (32 B,
//   clamp folded) into d_ws. Main-kernel bilerp = 2 loads at ONE address.
//   Deep software pipeline: coords 3-4 batches ahead, patch loads 1-2 ahead,
//   features staged to ping-pong featbuf 1 ahead. Phases A/B as R6
//   (barrier-free, wave-private LDS, weights resident as MFMA A-fragments).

#define NTHREADS 256
#define NB 4                  // 64-point batches per wave
#define LSTRIDE 72            // shorts per transpose row (144 B, 16B-aligned)
#define WAVE_L (64 * LSTRIDE) // 9216 B per wave

typedef __attribute__((ext_vector_type(8))) short bf16x8;
typedef __attribute__((ext_vector_type(4))) float f32x4;
typedef __attribute__((ext_vector_type(4))) int i32x4;
typedef __attribute__((ext_vector_type(2))) int i32x2;

static __device__ __forceinline__ short f2bf(float f) {
    return __builtin_bit_cast(short, __float2bfloat16(f));  // RNE
}
static __device__ __forceinline__ int pk2(float lo, float hi) {
    unsigned short l = (unsigned short)f2bf(lo);
    unsigned short h = (unsigned short)f2bf(hi);
    return (int)(((unsigned int)h << 16) | (unsigned int)l);
}
static __device__ __forceinline__ float bflo(int u) {
    return __builtin_bit_cast(float, u << 16);
}
static __device__ __forceinline__ float bfhi(int u) {
    return __builtin_bit_cast(float, (int)(u & 0xffff0000));
}

// ---- preproc: pack 2x2 corner patches (bf16) ----
// patch[id=(y0<<8)|x0]: int[8]: [0..2]=(bl<<16)|tl per ch, [3..5]=(br<<16)|tr,
// [6..7] pad. Clamp x1/y1 folded in.
__global__ __launch_bounds__(256) void make_patches(
    const float* __restrict__ g, int* __restrict__ pout) {
    int id = blockIdx.x * 256 + threadIdx.x;  // 0..65535
    int y0 = id >> 8, x0 = id & 255;
    int x1 = min(x0 + 1, 255), y1 = min(y0 + 1, 255);
    const float* tl = g + (y0 * 256 + x0) * 3;
    const float* tr = g + (y0 * 256 + x1) * 3;
    const float* bl = g + (y1 * 256 + x0) * 3;
    const float* br = g + (y1 * 256 + x1) * 3;
    i32x4 u0;
    i32x2 u1;
    u0[0] = pk2(tl[0], bl[0]);
    u0[1] = pk2(tl[1], bl[1]);
    u0[2] = pk2(tl[2], bl[2]);
    u0[3] = pk2(tr[0], br[0]);
    u1[0] = pk2(tr[1], br[1]);
    u1[1] = pk2(tr[2], br[2]);
    *(i32x4*)(pout + id * 8) = u0;
    *(i32x2*)(pout + id * 8 + 4) = u1;
}

static __device__ __forceinline__ void patch_issue(
    const int* __restrict__ tab, float px, float py, int* P, float& xf,
    float& yf) {
    float fx = px * 255.0f;
    float fy = py * 255.0f;
    int x0 = (int)fx;            // trunc, fx >= 0
    int y0 = (int)fy;
    xf = fx - floorf(fx);        // jnp.mod(fx,1.0), fx >= 0
    yf = fy - floorf(fy);
    int idx = (y0 << 8) | x0;
    i32x4 a = *(const i32x4*)(tab + idx * 8);
    i32x2 b = *(const i32x2*)(tab + idx * 8 + 4);
    P[0] = a[0]; P[1] = a[1]; P[2] = a[2];
    P[3] = a[3]; P[4] = b[0]; P[5] = b[1];
}

static __device__ __forceinline__ void patch_lerp(const int* P, float xf,
                                                  float yf, float* f) {
#pragma unroll
    for (int ch = 0; ch < 3; ++ch) {
        float tl = bflo(P[ch]), bl = bfhi(P[ch]);
        float tr = bflo(P[ch + 3]), br = bfhi(P[ch + 3]);
        float top = fmaf(xf, tr - tl, tl);
        float bot = fmaf(xf, br - bl, bl);
        f[ch] = fmaf(yf, bot - top, top);
    }
}

__global__ __launch_bounds__(NTHREADS, 3) void mlp_mfma_kernel(
    const float* __restrict__ pos, const float* __restrict__ dir,
    const int* __restrict__ patP, const int* __restrict__ patD,
    const float* __restrict__ W1, const float* __restrict__ b1,
    const float* __restrict__ W2, const float* __restrict__ b2,
    const float* __restrict__ W3, const float* __restrict__ b3,
    float* __restrict__ out) {
    __shared__ short lds_L[4 * WAVE_L];    // transpose buffers, 36864 B
    __shared__ int lds_F[4 * 2 * 64 * 4];  // feature ping-pong, 8192 B

    const int w = threadIdx.x >> 6;
    const int lane = threadIdx.x & 63;
    const int c = lane & 15;
    const int q = lane >> 4;

    short* L = lds_L + w * WAVE_L;
    int* FB = lds_F + w * (2 * 64 * 4);

    // ---- resident weight fragments (weights are the MFMA A operand) ----
    bf16x8 A1f[4];
#pragma unroll
    for (int mt = 0; mt < 4; ++mt) {
        int f = mt * 16 + c;
        bf16x8 t;
#pragma unroll
        for (int j = 0; j < 8; ++j) {
            float v = 0.0f;
            if (q == 0) {
                if (j < 6) v = W1[f * 6 + j];
                else if (j == 6) v = b1[f];
            }
            t[j] = f2bf(v);
        }
        A1f[mt] = t;
    }
    bf16x8 A2f[2][4];
#pragma unroll
    for (int kt = 0; kt < 2; ++kt)
#pragma unroll
        for (int mt = 0; mt < 4; ++mt) {
            int n2 = mt * 16 + c;
            int k0 = kt * 32 + q * 8;
            bf16x8 t;
#pragma unroll
            for (int j = 0; j < 8; ++j) t[j] = f2bf(W2[n2 * 64 + k0 + j]);
            A2f[kt][mt] = t;
        }
    f32x4 ci[4], w3q[4];
#pragma unroll
    for (int ft = 0; ft < 4; ++ft)
#pragma unroll
        for (int r = 0; r < 4; ++r) {
            ci[ft][r] = b2[ft * 16 + q * 4 + r];
            w3q[ft][r] = W3[ft * 16 + q * 4 + r];
        }
    const float b3s = b3[0];
    const int dbias = pk2(1.0f, 0.0f);

    const long wave_global = (long)blockIdx.x * 4 + w;
    const long base0 = wave_global * (64L * NB);
    const f32x4 zacc = {0.f, 0.f, 0.f, 0.f};
    const float2* pos2 = (const float2*)pos;
    const float2* dir2 = (const float2*)dir;

    // ---- pipeline state ----
    int PA[12], PB[12];        // patches for batch ib+1 / ib+2 (pos 0..5, dir 6..11)
    float frA[4], frB[4];      // xf,yf (pos then dir) for batch ib+1 / ib+2
    float2 cp2, cd2, cp3, cd3; // coords for batch ib+2 / ib+3

    // ---- prologue ----
    {
        float2 c0p = pos2[base0 + lane], c0d = dir2[base0 + lane];
        float2 c1p = pos2[base0 + 64 + lane], c1d = dir2[base0 + 64 + lane];
        cp2 = pos2[base0 + 128 + lane];
        cd2 = dir2[base0 + 128 + lane];
        cp3 = pos2[base0 + 192 + lane];
        cd3 = dir2[base0 + 192 + lane];
        // batch 0: patches -> features -> featbuf[0]
        int P0_[12];
        float fr0[4];
        patch_issue(patP, c0p.x, c0p.y, P0_, fr0[0], fr0[1]);
        patch_issue(patD, c0d.x, c0d.y, P0_ + 6, fr0[2], fr0[3]);
        float feat[6];
        patch_lerp(P0_, fr0[0], fr0[1], feat);
        patch_lerp(P0_ + 6, fr0[2], fr0[3], feat + 3);
        i32x4 dv;
        dv[0] = pk2(feat[0], feat[1]);
        dv[1] = pk2(feat[2], feat[3]);
        dv[2] = pk2(feat[4], feat[5]);
        dv[3] = dbias;
        *(i32x4*)(FB + lane * 4) = dv;
        // batch 1 patches (consumed at iter 0)
        patch_issue(patP, c1p.x, c1p.y, PA, frA[0], frA[1]);
        patch_issue(patD, c1d.x, c1d.y, PA + 6, frA[2], frA[3]);
    }

#pragma unroll 1
    for (int ib = 0; ib < NB; ++ib) {
        const long base = base0 + ib * 64;
        const int cur = ib & 1;

        // issue patches for batch ib+2
        patch_issue(patP, cp2.x, cp2.y, PB, frB[0], frB[1]);
        patch_issue(patD, cd2.x, cd2.y, PB + 6, frB[2], frB[3]);

        // features for batch ib+1 (patches issued one full iter ago)
        {
            float feat[6];
            patch_lerp(PA, frA[0], frA[1], feat);
            patch_lerp(PA + 6, frA[2], frA[3], feat + 3);
            i32x4 dv;
            dv[0] = pk2(feat[0], feat[1]);
            dv[1] = pk2(feat[2], feat[3]);
            dv[2] = pk2(feat[4], feat[5]);
            dv[3] = dbias;
            *(i32x4*)(FB + (cur ^ 1) * 256 + lane * 4) = dv;
        }

        // ---- phase A: layer 1 for 4 pt tiles + transpose writes ----
#pragma unroll
        for (int pt = 0; pt < 4; ++pt) {
            const int row = pt * 16 + c;
            i32x4 bi = *(const i32x4*)(FB + cur * 256 + row * 4);
            bf16x8 bfrag = __builtin_bit_cast(bf16x8, bi);
            f32x4 a1[4];
#pragma unroll
            for (int mt = 0; mt < 4; ++mt)
                a1[mt] = __builtin_amdgcn_mfma_f32_16x16x32_bf16(
                    A1f[mt], bfrag, zacc, 0, 0, 0);
#pragma unroll
            for (int mt = 0; mt < 4; ++mt) {
                float l0 = a1[mt][0], l1 = a1[mt][1];
                float l2 = a1[mt][2], l3 = a1[mt][3];
                l0 = fmaxf(l0, 0.01f * l0);
                l1 = fmaxf(l1, 0.01f * l1);
                l2 = fmaxf(l2, 0.01f * l2);
                l3 = fmaxf(l3, 0.01f * l3);
                i32x2 wv;
                wv[0] = pk2(l0, l1);
                wv[1] = pk2(l2, l3);
                *(i32x2*)(L + row * LSTRIDE + mt * 16 + q * 4) = wv;
            }
        }

        // ---- phase B: layer 2 + epilogue ----
        float s[4];
#pragma unroll
        for (int pt = 0; pt < 4; ++pt) {
            const int row = pt * 16 + c;
            bf16x8 h0 = *(const bf16x8*)(L + row * LSTRIDE + q * 8);
            bf16x8 h1 = *(const bf16x8*)(L + row * LSTRIDE + 32 + q * 8);
            float t = 0.0f;
#pragma unroll
            for (int ft = 0; ft < 4; ++ft) {
                f32x4 t0 = __builtin_amdgcn_mfma_f32_16x16x32_bf16(
                    A2f[0][ft], h0, ci[ft], 0, 0, 0);  // C = b2 directly
                f32x4 a2 = __builtin_amdgcn_mfma_f32_16x16x32_bf16(
                    A2f[1][ft], h1, t0, 0, 0, 0);
#pragma unroll
                for (int r = 0; r < 4; ++r) {
                    float x = a2[r];
                    x = fmaxf(x, 0.01f * x);
                    t = fmaf(x, w3q[ft][r], t);
                }
            }
            t += __shfl_xor(t, 16, 64);
            t += __shfl_xor(t, 32, 64);
            s[pt] = t;
        }

        float sa = (q & 1) ? s[1] : s[0];
        float sb = (q & 1) ? s[3] : s[2];
        float v = (q & 2) ? sb : sa;
        v += b3s;
        v = 1.0f / (1.0f + __expf(-v));
        out[base + q * 16 + c] = v;

        // ---- rotate pipeline ----
#pragma unroll
        for (int i2 = 0; i2 < 12; ++i2) PA[i2] = PB[i2];
        frA[0] = frB[0]; frA[1] = frB[1]; frA[2] = frB[2]; frA[3] = frB[3];
        cp2 = cp3;
        cd2 = cd3;
        int mb = min(ib + 4, NB - 1);
        cp3 = pos2[base0 + mb * 64 + lane];
        cd3 = dir2[base0 + mb * 64 + lane];
    }
}

extern "C" void kernel_launch(void* const* d_in, const int* in_sizes, int n_in,
                              void* d_out, int out_size, void* d_ws,
                              size_t ws_size, hipStream_t stream) {
    const float* pos = (const float*)d_in[0];
    const float* dir = (const float*)d_in[1];
    const float* pos_grid = (const float*)d_in[2];
    const float* dir_grid = (const float*)d_in[3];
    const float* W1 = (const float*)d_in[4];
    const float* b1 = (const float*)d_in[5];
    const float* W2 = (const float*)d_in[6];
    const float* b2 = (const float*)d_in[7];
    const float* W3 = (const float*)d_in[8];
    const float* b3 = (const float*)d_in[9];
    float* out = (float*)d_out;

    int* patP = (int*)d_ws;             // 65536 * 32 B = 2 MB
    int* patD = patP + 65536 * 8;       // 2 MB

    make_patches<<<256, 256, 0, stream>>>(pos_grid, patP);
    make_patches<<<256, 256, 0, stream>>>(dir_grid, patD);

    const int n = in_sizes[0] / 2;   // points
    const int batches = n / 64;      // 32768 for N=2M
    const int waves = batches / NB;  // 8192
    const int blocks = waves / 4;    // 2048

    mlp_mfma_kernel<<<blocks, NTHREADS, 0, stream>>>(
        pos, dir, patP, patD, W1, b1, W2, b2, W3, b3, out);
}